// Round 12
// baseline (470.979 us; speedup 1.0000x reference)
//
#include <hip/hip_runtime.h>
#include <hip/hip_cooperative_groups.h>
#include <math.h>

namespace cg = cooperative_groups;

constexpr int kB   = 128;
constexpr int kP   = 2048;
constexpr int kRES = 4096;
constexpr int kF   = 256;
constexpr int kH   = 1024;
constexpr float kLN_EPS = 1e-5f;
constexpr int kBN = 32;    // k3 cols per n-tile
constexpr int kBK = 64;    // fallback k3 K sub-chunk
constexpr int kBK2 = 32;   // mega k3 K sub-chunk (LDS budget)
constexpr int kRSTD_BLOCKS = 512;
// mega-kernel fixed geometry
constexpr int kCm  = 4096;                                   // chains
constexpr int kKm  = (kB * kP + kCm - 129) / (kCm - 128);    // = 67
constexpr int kKTm = 8;                                      // split-K

#if __has_builtin(__builtin_amdgcn_exp2f)
#define EXP2F __builtin_amdgcn_exp2f
#else
#define EXP2F exp2f
#endif
#if __has_builtin(__builtin_amdgcn_rcpf)
#define RCPF __builtin_amdgcn_rcpf
#else
#define RCPF(x) (1.0f / (x))
#endif

__device__ __forceinline__ float gelu_fast(float y) {
    const float a = fabsf(y);
    const float t = RCPF(fmaf(0.33267096f, a, 1.0f));
    const float e = EXP2F(-0.72134752f * y * y);
    const float p = fmaf(fmaf(0.37392780f, t, -0.04793990f), t, 0.17401210f);
    const float w = (p * t) * e;
    return fmaf(-a, w, fmaf(0.5f, y, 0.5f * a));
}

__device__ __forceinline__ void build_chain_starts(
    const int* __restrict__ plen, int C, int K, int tid,
    unsigned* s1, unsigned* s2, int* cs)
{
    if (tid < kB) s1[tid] = (unsigned)plen[tid] + (unsigned)K;
    __syncthreads();
    unsigned* src = s1; unsigned* dst = s2;
    #pragma unroll
    for (int d = 1; d < kB; d <<= 1) {
        if (tid < kB) dst[tid] = src[tid] + ((tid >= d) ? src[tid - d] : 0u);
        __syncthreads();
        unsigned* t = src; src = dst; dst = t;
    }
    const unsigned total = src[kB - 1];
    if (tid <= kB) {
        const unsigned pre = (tid == 0) ? 0u : src[tid - 1];
        cs[tid] = (int)(((unsigned long long)pre * (unsigned)C) / total);
    }
    __syncthreads();
}

__device__ __forceinline__ void ln_constants(
    const float* __restrict__ W1, const float* __restrict__ b1,
    int tid, float pr[14][4], float* cl)
{
    const float w0 = W1[tid], w1 = W1[256 + tid], w2 = W1[512 + tid], bb = b1[tid];
    float v[14] = { w0, w1, w2, bb, w0*w0, w0*w1, w0*w2, w1*w1, w1*w2, w2*w2,
                    w0*bb, w1*bb, w2*bb, bb*bb };
    #pragma unroll
    for (int off = 32; off; off >>= 1) {
        #pragma unroll
        for (int i = 0; i < 14; ++i) v[i] += __shfl_xor(v[i], off);
    }
    if ((tid & 63) == 0) {
        #pragma unroll
        for (int i = 0; i < 14; ++i) pr[i][tid >> 6] = v[i];
    }
    __syncthreads();
    if (tid < 14)
        cl[tid] = (pr[tid][0] + pr[tid][1] + pr[tid][2] + pr[tid][3]) * (1.f / 256.f);
    __syncthreads();
}

// ROW body shared by k1 variants
#define ROW(x0, x1, x2, rs)                                                      \
    {                                                                            \
        const float h0 = fmaf((x2), w2q.x, fmaf((x1), w1q.x, fmaf((x0), w0q.x, bpq.x))); \
        const float h1 = fmaf((x2), w2q.y, fmaf((x1), w1q.y, fmaf((x0), w0q.y, bpq.y))); \
        const float h2 = fmaf((x2), w2q.z, fmaf((x1), w1q.z, fmaf((x0), w0q.z, bpq.z))); \
        const float h3 = fmaf((x2), w2q.w, fmaf((x1), w1q.w, fmaf((x0), w0q.w, bpq.w))); \
        a0 += gelu_fast(fmaf(h0, (rs), beq.x));                                  \
        a1 += gelu_fast(fmaf(h1, (rs), beq.y));                                  \
        a2 += gelu_fast(fmaf(h2, (rs), beq.z));                                  \
        a3 += gelu_fast(fmaf(h3, (rs), beq.w));                                  \
    }

// ===========================================================================
// MEGA cooperative kernel: all phases in one launch, grid 1024 x 256.
// Phase0 setup+rstd | Phase1 k1 | Phase2 k2 | Phase3 k3a(kBK2) | Phase4 k3b.
// ===========================================================================
__global__ __launch_bounds__(256, 4) void mega_kernel(
    const float* __restrict__ pd, const int* __restrict__ plen,
    const int* __restrict__ betti, const float* __restrict__ pimg,
    const float* __restrict__ W1, const float* __restrict__ b1,
    const float* __restrict__ lng, const float* __restrict__ lnb,
    const float* __restrict__ W2, const float* __restrict__ b2,
    const float* __restrict__ btab, const float* __restrict__ cw,
    const float* __restrict__ cb, const float* __restrict__ Wo,
    const float* __restrict__ bo, float* __restrict__ out,
    float* __restrict__ partial, float* __restrict__ combined,
    float* __restrict__ Wp, float* __restrict__ bp,
    int* __restrict__ cs_g, int4* __restrict__ ctab,
    float* __restrict__ rstdb)
{
    __shared__ unsigned s1[kB], s2[kB];
    __shared__ int cs[kB + 1];
    __shared__ float pr[14][4];
    __shared__ float cl[14];
    __shared__ float red[4 * 256];
    __shared__ float ml[256];
    __shared__ float sred[2][4];
    __shared__ float At[kBK2 * 132];
    __shared__ float Bs[kBK2 * kBN];

    cg::grid_group grid = cg::this_grid();
    const int bid = blockIdx.x;
    const int tid = threadIdx.x;
    const int lane = tid & 63, wave = tid >> 6;

    // ---------------- Phase 0: constants + rstd + tables ----------------
    ln_constants(W1, b1, tid, pr, cl);
    {
        const float S0 = cl[0], S1c = cl[1], S2c = cl[2], Sb = cl[3];
        const float P00 = cl[4], P01 = cl[5], P02 = cl[6];
        const float P11 = cl[7], P12 = cl[8], P22 = cl[9];
        const float Q0 = cl[10], Q1 = cl[11], Q2 = cl[12], Rc = cl[13];
        const int r = bid * 256 + tid;                 // 1024*256 = 262144 rows
        const float* rp = pd + (size_t)r * 3;
        const float x0 = rp[0], x1 = rp[1], x2 = rp[2];
        const float mu = fmaf(x2, S2c, fmaf(x1, S1c, fmaf(x0, S0, Sb)));
        const float sx = fmaf(P01 * x0, x1, fmaf(P02 * x0, x2, fmaf(P12 * x1, x2,
                         fmaf(Q0, x0, fmaf(Q1, x1, Q2 * x2)))));
        const float e2 = fmaf(P00 * x0, x0, fmaf(P11 * x1, x1, fmaf(P22 * x2, x2,
                         fmaf(2.f, sx, Rc))));
        rstdb[r] = rsqrtf(fmaf(-mu, mu, e2) + kLN_EPS);
    }
    if (bid < (kCm >> 8)) {                            // blocks 0..15: tables
        build_chain_starts(plen, kCm, kKm, tid, s1, s2, cs);
        const int c = bid * 256 + tid;
        int lo = 0, hi = kB;
        while (hi - lo > 1) { const int mid = (lo + hi) >> 1; if (cs[mid] <= c) lo = mid; else hi = mid; }
        const int b = lo;
        const int m = cs[b + 1] - cs[b];
        const int j = c - cs[b];
        const int len = plen[b];
        const int T  = (len + 3) >> 2;
        const int l4 = (int)(((long long)j * T) / m);
        const int h4 = (int)(((long long)(j + 1) * T) / m);
        const int start = min(l4 * 4, len);
        const int cnt   = max(0, min(h4 * 4, len) - start);
        ctab[c] = make_int4(b, start, cnt, 0);
        if (bid == 0) {
            if (tid <= kB) cs_g[tid] = cs[tid];
            const float g = lng[tid];
            Wp[tid]       = (W1[tid]       - cl[0]) * g;
            Wp[256 + tid] = (W1[256 + tid] - cl[1]) * g;
            Wp[512 + tid] = (W1[512 + tid] - cl[2]) * g;
            bp[tid]       = (b1[tid]       - cl[3]) * g;
        }
    }
    grid.sync();

    // ---------------- Phase 1: k1 (all blocks, wave = chain) ----------------
    {
        const int c = bid * 4 + wave;                  // 0..4095
        const int4 ci = ctab[c];
        const int b = ci.x, start = ci.y, cnt = ci.z;
        const float4 w0q = ((const float4*)Wp)[lane];
        const float4 w1q = ((const float4*)Wp)[64 + lane];
        const float4 w2q = ((const float4*)Wp)[128 + lane];
        const float4 bpq = ((const float4*)bp)[lane];
        const float4 beq = ((const float4*)lnb)[lane];
        float a0 = 0.f, a1 = 0.f, a2 = 0.f, a3 = 0.f;
        const int nq  = cnt >> 2;
        const int rem = cnt & 3;
        const float4* qp = (const float4*)(pd + ((size_t)b * kP + start) * 3);
        const float4* rs4 = (const float4*)(rstdb + (size_t)b * kP + start);
        for (int it = 0; it < nq; ++it) {
            const float4 f0 = qp[0];
            const float4 f1 = qp[1];
            const float4 f2 = qp[2];
            const float4 rq = rs4[it];
            qp += 3;
            ROW(f0.x, f0.y, f0.z, rq.x);
            ROW(f0.w, f1.x, f1.y, rq.y);
            ROW(f1.z, f1.w, f2.x, rq.z);
            ROW(f2.y, f2.z, f2.w, rq.w);
        }
        const float* rp = (const float*)qp;
        const float* rsp = rstdb + (size_t)b * kP + start + nq * 4;
        for (int it = 0; it < rem; ++it, rp += 3) {
            ROW(rp[0], rp[1], rp[2], rsp[it]);
        }
        ((float4*)(partial + ((size_t)c << 8)))[lane] = make_float4(a0, a1, a2, a3);
    }
    grid.sync();

    // ---------------- Phase 2: k2 (blocks 0..255) ----------------
    if (bid < 2 * kB) {
        const int b = bid >> 1;
        if ((bid & 1) == 0) {
            const int len = plen[b];
            const int c0 = cs_g[b], c1 = cs_g[b + 1];
            float4 aq = make_float4(0.f, 0.f, 0.f, 0.f);
            float4 bq = make_float4(0.f, 0.f, 0.f, 0.f);
            int c = c0 + wave;
            for (; c + 4 < c1; c += 8) {
                const float4 v0 = ((const float4*)(partial + ((size_t)c << 8)))[lane];
                const float4 v1 = ((const float4*)(partial + ((size_t)(c + 4) << 8)))[lane];
                aq.x += v0.x; aq.y += v0.y; aq.z += v0.z; aq.w += v0.w;
                bq.x += v1.x; bq.y += v1.y; bq.z += v1.z; bq.w += v1.w;
            }
            if (c < c1) {
                const float4 v0 = ((const float4*)(partial + ((size_t)c << 8)))[lane];
                aq.x += v0.x; aq.y += v0.y; aq.z += v0.z; aq.w += v0.w;
            }
            aq.x += bq.x; aq.y += bq.y; aq.z += bq.z; aq.w += bq.w;
            ((float4*)red)[wave * 64 + lane] = aq;
            __syncthreads();
            const float inv = (len > 0) ? (1.f / (float)len) : 0.f;
            ml[tid] = (red[tid] + red[256 + tid] + red[512 + tid] + red[768 + tid]) * inv;
            __syncthreads();
            const float4* W24 = (const float4*)W2;
            float4 acc = make_float4(0.f, 0.f, 0.f, 0.f);
            const int f0 = wave * 64;
            #pragma unroll 8
            for (int i = 0; i < 64; ++i) {
                const float mv = ml[f0 + i];
                const float4 wv = W24[(size_t)(f0 + i) * 64 + lane];
                acc.x = fmaf(mv, wv.x, acc.x); acc.y = fmaf(mv, wv.y, acc.y);
                acc.z = fmaf(mv, wv.z, acc.z); acc.w = fmaf(mv, wv.w, acc.w);
            }
            ((float4*)red)[wave * 64 + lane] = acc;
            __syncthreads();
            const float o = (red[tid] + red[256 + tid]) + (red[512 + tid] + red[768 + tid]);
            combined[(size_t)b * kH + tid] = (len > 0) ? (o + b2[tid]) : 0.f;
            const int i0 = min(max(betti[b * 3 + 0], 0), 9);
            const int i1 = min(max(betti[b * 3 + 1], 0), 9);
            const int i2 = min(max(betti[b * 3 + 2], 0), 9);
            combined[(size_t)b * kH + 256 + tid] =
                (btab[i0 * 256 + tid] + btab[i1 * 256 + tid] +
                 btab[i2 * 256 + tid]) * (1.f / 3.f);
        } else {
            const float4* x4 = (const float4*)(pimg + (size_t)b * kRES);
            float se = 0.f, so = 0.f;
            #pragma unroll
            for (int j = 0; j < 4; ++j) {
                const float4 v = x4[tid + j * 256];
                se += v.x + v.z;
                so += v.y + v.w;
            }
            #pragma unroll
            for (int off = 32; off; off >>= 1) {
                se += __shfl_xor(se, off);
                so += __shfl_xor(so, off);
            }
            if (lane == 0) { sred[0][wave] = se; sred[1][wave] = so; }
            __syncthreads();
            se = (sred[0][0] + sred[0][1]) + (sred[0][2] + sred[0][3]);
            so = (sred[1][0] + sred[1][1]) + (sred[1][2] + sred[1][3]);
            const float x0 = pimg[(size_t)b * kRES + 0];
            const float xe = pimg[(size_t)b * kRES + 4094];
            const float xo = pimg[(size_t)b * kRES + 4095];
            #pragma unroll
            for (int u = 0; u < 2; ++u) {
                const int cc = tid + u * 256;
                const float* w = cw + (size_t)cc * 5;
                const float v = w[0] * (se - xe) + w[1] * (so - xo) + w[2] * se +
                                w[3] * so + w[4] * (se - x0);
                combined[(size_t)b * kH + 512 + cc] = v * (1.f / 2048.f) + cb[cc];
            }
        }
    }
    grid.sync();

    // ---------------- Phase 3: k3a (blocks 0..255), kpart = partial ----------------
    float* kpart = partial;
    if (bid < 32 * kKTm) {
        const int nt = bid & 31;
        const int kt = bid >> 5;
        const int n0 = nt * kBN;
        const int kchunk = kH / kKTm;                  // 128
        const int nsub   = kchunk / kBK2;              // 4
        const int n8 = tid & 7;
        const int mg = tid >> 3;
        float4 acc0 = make_float4(0.f,0.f,0.f,0.f);
        float4 acc1 = make_float4(0.f,0.f,0.f,0.f);
        float4 acc2 = make_float4(0.f,0.f,0.f,0.f);
        float4 acc3 = make_float4(0.f,0.f,0.f,0.f);
        for (int sc = 0; sc < nsub; ++sc) {
            const int k0 = kt * kchunk + sc * kBK2;
            __syncthreads();
            #pragma unroll
            for (int it = 0; it < 4; ++it) {
                const int idx = it * 256 + tid;        // 0..1023
                const int m   = idx >> 3;              // 0..127
                const int c4  = idx & 7;               // 0..7
                const float4 v = *(const float4*)(combined + (size_t)m * kH + k0 + c4 * 4);
                At[(c4 * 4 + 0) * 132 + m] = v.x;
                At[(c4 * 4 + 1) * 132 + m] = v.y;
                At[(c4 * 4 + 2) * 132 + m] = v.z;
                At[(c4 * 4 + 3) * 132 + m] = v.w;
            }
            {
                const int kk  = tid >> 3;              // 0..31
                const int ccc = tid & 7;
                *(float4*)(Bs + kk * kBN + ccc * 4) =
                    *(const float4*)(Wo + (size_t)(k0 + kk) * kH + n0 + ccc * 4);
            }
            __syncthreads();
            #pragma unroll 8
            for (int kk = 0; kk < kBK2; ++kk) {
                const float4 av = *(const float4*)(At + kk * 132 + mg * 4);
                const float4 bv = *(const float4*)(Bs + kk * kBN + n8 * 4);
                acc0.x = fmaf(av.x, bv.x, acc0.x); acc0.y = fmaf(av.x, bv.y, acc0.y);
                acc0.z = fmaf(av.x, bv.z, acc0.z); acc0.w = fmaf(av.x, bv.w, acc0.w);
                acc1.x = fmaf(av.y, bv.x, acc1.x); acc1.y = fmaf(av.y, bv.y, acc1.y);
                acc1.z = fmaf(av.y, bv.z, acc1.z); acc1.w = fmaf(av.y, bv.w, acc1.w);
                acc2.x = fmaf(av.z, bv.x, acc2.x); acc2.y = fmaf(av.z, bv.y, acc2.y);
                acc2.z = fmaf(av.z, bv.z, acc2.z); acc2.w = fmaf(av.z, bv.w, acc2.w);
                acc3.x = fmaf(av.w, bv.x, acc3.x); acc3.y = fmaf(av.w, bv.y, acc3.y);
                acc3.z = fmaf(av.w, bv.z, acc3.z); acc3.w = fmaf(av.w, bv.w, acc3.w);
            }
        }
        float* base = kpart + ((size_t)kt * kB + mg * 4) * kH + n0 + n8 * 4;
        *(float4*)(base)          = acc0;
        *(float4*)(base + kH)     = acc1;
        *(float4*)(base + 2 * kH) = acc2;
        *(float4*)(base + 3 * kH) = acc3;
    }
    grid.sync();

    // ---------------- Phase 4: k3b (blocks 0..127) ----------------
    if (bid < kB) {
        const int g = bid * 256 + tid;
        const float4* kp = (const float4*)kpart;
        float4 a = make_float4(0.f, 0.f, 0.f, 0.f);
        float4 b4 = make_float4(0.f, 0.f, 0.f, 0.f);
        #pragma unroll
        for (int t = 0; t < kKTm; t += 2) {
            const float4 v0 = kp[(size_t)(t + 0) * (kB * kH / 4) + g];
            const float4 v1 = kp[(size_t)(t + 1) * (kB * kH / 4) + g];
            a.x += v0.x; a.y += v0.y; a.z += v0.z; a.w += v0.w;
            b4.x += v1.x; b4.y += v1.y; b4.z += v1.z; b4.w += v1.w;
        }
        a.x += b4.x; a.y += b4.y; a.z += b4.z; a.w += b4.w;
        const float4 bq = ((const float4*)bo)[g & 255];
        a.x += bq.x; a.y += bq.y; a.z += bq.z; a.w += bq.w;
        ((float4*)out)[g] = a;
    }
}

// ===========================================================================
// FALLBACK path: round-9 kernels verbatim (proven 52.4 us).
// ===========================================================================
__global__ __launch_bounds__(256) void k0_setup(
    const int* __restrict__ plen, const float* __restrict__ W1,
    const float* __restrict__ b1, const float* __restrict__ ln_g,
    const float* __restrict__ pd,
    float* __restrict__ Wp, float* __restrict__ bp,
    int* __restrict__ cs_g, int4* __restrict__ ctab,
    float* __restrict__ rstdb, int C, int K)
{
    __shared__ unsigned s1[kB], s2[kB];
    __shared__ int cs[kB + 1];
    __shared__ float pr[14][4];
    __shared__ float cl[14];
    const int tid = threadIdx.x;
    const int bid = blockIdx.x;
    const int NB_TAB = C >> 8;

    if (bid >= NB_TAB) {
        ln_constants(W1, b1, tid, pr, cl);
        const float S0 = cl[0], S1c = cl[1], S2c = cl[2], Sb = cl[3];
        const float P00 = cl[4], P01 = cl[5], P02 = cl[6];
        const float P11 = cl[7], P12 = cl[8], P22 = cl[9];
        const float Q0 = cl[10], Q1 = cl[11], Q2 = cl[12], Rc = cl[13];
        const int rbase = (bid - NB_TAB) * 512;
        #pragma unroll
        for (int u = 0; u < 2; ++u) {
            const int r = rbase + u * 256 + tid;
            const float* rp = pd + (size_t)r * 3;
            const float x0 = rp[0], x1 = rp[1], x2 = rp[2];
            const float mu = fmaf(x2, S2c, fmaf(x1, S1c, fmaf(x0, S0, Sb)));
            const float sx = fmaf(P01 * x0, x1, fmaf(P02 * x0, x2, fmaf(P12 * x1, x2,
                             fmaf(Q0, x0, fmaf(Q1, x1, Q2 * x2)))));
            const float e2 = fmaf(P00 * x0, x0, fmaf(P11 * x1, x1, fmaf(P22 * x2, x2,
                             fmaf(2.f, sx, Rc))));
            rstdb[r] = rsqrtf(fmaf(-mu, mu, e2) + kLN_EPS);
        }
        return;
    }

    build_chain_starts(plen, C, K, tid, s1, s2, cs);
    const int c = bid * 256 + tid;
    {
        int lo = 0, hi = kB;
        while (hi - lo > 1) { const int mid = (lo + hi) >> 1; if (cs[mid] <= c) lo = mid; else hi = mid; }
        const int b = lo;
        const int m = cs[b + 1] - cs[b];
        const int j = c - cs[b];
        const int len = plen[b];
        const int T  = (len + 3) >> 2;
        const int l4 = (int)(((long long)j * T) / m);
        const int h4 = (int)(((long long)(j + 1) * T) / m);
        const int start = min(l4 * 4, len);
        const int cnt   = max(0, min(h4 * 4, len) - start);
        ctab[c] = make_int4(b, start, cnt, 0);
    }
    if (bid == 0) {
        if (tid <= kB) cs_g[tid] = cs[tid];
        ln_constants(W1, b1, tid, pr, cl);
        const float g = ln_g[tid];
        Wp[tid]       = (W1[tid]       - cl[0]) * g;
        Wp[256 + tid] = (W1[256 + tid] - cl[1]) * g;
        Wp[512 + tid] = (W1[512 + tid] - cl[2]) * g;
        bp[tid]       = (b1[tid]       - cl[3]) * g;
    }
}

__global__ __launch_bounds__(256) void k1_pd_partial(
    const float* __restrict__ pd, const float* __restrict__ Wp,
    const float* __restrict__ bp, const float* __restrict__ ln_b,
    const int4* __restrict__ ctab, const float* __restrict__ rstdb,
    float* __restrict__ partial)
{
    const int tid = threadIdx.x, lane = tid & 63, wave = tid >> 6;
    const int c = blockIdx.x * 4 + wave;
    const int4 ci = ctab[c];
    const int b = ci.x, start = ci.y, cnt = ci.z;

    const float4 w0q = ((const float4*)Wp)[lane];
    const float4 w1q = ((const float4*)Wp)[64 + lane];
    const float4 w2q = ((const float4*)Wp)[128 + lane];
    const float4 bpq = ((const float4*)bp)[lane];
    const float4 beq = ((const float4*)ln_b)[lane];

    float a0 = 0.f, a1 = 0.f, a2 = 0.f, a3 = 0.f;
    const int nq  = cnt >> 2;
    const int rem = cnt & 3;
    const float4* qp = (const float4*)(pd + ((size_t)b * kP + start) * 3);
    const float4* rs4 = (const float4*)(rstdb + (size_t)b * kP + start);
    for (int it = 0; it < nq; ++it) {
        const float4 f0 = qp[0];
        const float4 f1 = qp[1];
        const float4 f2 = qp[2];
        const float4 rq = rs4[it];
        qp += 3;
        ROW(f0.x, f0.y, f0.z, rq.x);
        ROW(f0.w, f1.x, f1.y, rq.y);
        ROW(f1.z, f1.w, f2.x, rq.z);
        ROW(f2.y, f2.z, f2.w, rq.w);
    }
    const float* rp = (const float*)qp;
    const float* rsp = rstdb + (size_t)b * kP + start + nq * 4;
    for (int it = 0; it < rem; ++it, rp += 3) {
        ROW(rp[0], rp[1], rp[2], rsp[it]);
    }
    ((float4*)(partial + ((size_t)c << 8)))[lane] = make_float4(a0, a1, a2, a3);
}

__global__ __launch_bounds__(256) void k2_combined(
    const float* __restrict__ partial, const int* __restrict__ plen,
    const float* __restrict__ W2, const float* __restrict__ b2,
    const int* __restrict__ betti, const float* __restrict__ betti_table,
    const float* __restrict__ pimg, const float* __restrict__ conv_w,
    const float* __restrict__ conv_b, float* __restrict__ combined,
    const int* __restrict__ cs_g)
{
    __shared__ float red[4 * 256];
    __shared__ float ml[256];
    __shared__ float sred[2][4];
    const int b    = blockIdx.x;
    const int tid  = threadIdx.x;
    const int wave = tid >> 6;
    const int lane = tid & 63;

    if (blockIdx.y == 0) {
        const int len = plen[b];
        const int c0 = cs_g[b], c1 = cs_g[b + 1];
        float4 aq = make_float4(0.f, 0.f, 0.f, 0.f);
        float4 bq = make_float4(0.f, 0.f, 0.f, 0.f);
        int c = c0 + wave;
        for (; c + 4 < c1; c += 8) {
            const float4 v0 = ((const float4*)(partial + ((size_t)c << 8)))[lane];
            const float4 v1 = ((const float4*)(partial + ((size_t)(c + 4) << 8)))[lane];
            aq.x += v0.x; aq.y += v0.y; aq.z += v0.z; aq.w += v0.w;
            bq.x += v1.x; bq.y += v1.y; bq.z += v1.z; bq.w += v1.w;
        }
        if (c < c1) {
            const float4 v0 = ((const float4*)(partial + ((size_t)c << 8)))[lane];
            aq.x += v0.x; aq.y += v0.y; aq.z += v0.z; aq.w += v0.w;
        }
        aq.x += bq.x; aq.y += bq.y; aq.z += bq.z; aq.w += bq.w;
        ((float4*)red)[wave * 64 + lane] = aq;
        __syncthreads();
        const float inv = (len > 0) ? (1.f / (float)len) : 0.f;
        ml[tid] = (red[tid] + red[256 + tid] + red[512 + tid] + red[768 + tid]) * inv;
        __syncthreads();
        const float4* W24 = (const float4*)W2;
        float4 acc = make_float4(0.f, 0.f, 0.f, 0.f);
        const int f0 = wave * 64;
        #pragma unroll 8
        for (int i = 0; i < 64; ++i) {
            const float mv = ml[f0 + i];
            const float4 wv = W24[(size_t)(f0 + i) * 64 + lane];
            acc.x = fmaf(mv, wv.x, acc.x); acc.y = fmaf(mv, wv.y, acc.y);
            acc.z = fmaf(mv, wv.z, acc.z); acc.w = fmaf(mv, wv.w, acc.w);
        }
        ((float4*)red)[wave * 64 + lane] = acc;
        __syncthreads();
        const float o = (red[tid] + red[256 + tid]) + (red[512 + tid] + red[768 + tid]);
        combined[(size_t)b * kH + tid] = (len > 0) ? (o + b2[tid]) : 0.f;
        const int i0 = min(max(betti[b * 3 + 0], 0), 9);
        const int i1 = min(max(betti[b * 3 + 1], 0), 9);
        const int i2 = min(max(betti[b * 3 + 2], 0), 9);
        combined[(size_t)b * kH + 256 + tid] =
            (betti_table[i0 * 256 + tid] + betti_table[i1 * 256 + tid] +
             betti_table[i2 * 256 + tid]) * (1.f / 3.f);
    } else {
        const float4* x4 = (const float4*)(pimg + (size_t)b * kRES);
        float se = 0.f, so = 0.f;
        #pragma unroll
        for (int j = 0; j < 4; ++j) {
            const float4 v = x4[tid + j * 256];
            se += v.x + v.z;
            so += v.y + v.w;
        }
        #pragma unroll
        for (int off = 32; off; off >>= 1) {
            se += __shfl_xor(se, off);
            so += __shfl_xor(so, off);
        }
        if (lane == 0) { sred[0][wave] = se; sred[1][wave] = so; }
        __syncthreads();
        se = (sred[0][0] + sred[0][1]) + (sred[0][2] + sred[0][3]);
        so = (sred[1][0] + sred[1][1]) + (sred[1][2] + sred[1][3]);
        const float x0 = pimg[(size_t)b * kRES + 0];
        const float xe = pimg[(size_t)b * kRES + 4094];
        const float xo = pimg[(size_t)b * kRES + 4095];
        #pragma unroll
        for (int u = 0; u < 2; ++u) {
            const int cc = tid + u * 256;
            const float* w = conv_w + (size_t)cc * 5;
            const float v = w[0] * (se - xe) + w[1] * (so - xo) + w[2] * se +
                            w[3] * so + w[4] * (se - x0);
            combined[(size_t)b * kH + 512 + cc] = v * (1.f / 2048.f) + conv_b[cc];
        }
    }
}

__global__ __launch_bounds__(256) void k3a_outproj(
    const float* __restrict__ combined, const float* __restrict__ Wo,
    float* __restrict__ kpart, int KT)
{
    const int nt  = blockIdx.x;
    const int kt  = blockIdx.y;
    const int tid = threadIdx.x;
    const int n0  = nt * kBN;
    const int kchunk = kH / KT;
    const int nsub   = kchunk / kBK;

    __shared__ float At[kBK * 132];
    __shared__ float Bs[kBK * kBN];

    const int n8 = tid & 7;
    const int mg = tid >> 3;

    float4 acc0 = make_float4(0.f,0.f,0.f,0.f);
    float4 acc1 = make_float4(0.f,0.f,0.f,0.f);
    float4 acc2 = make_float4(0.f,0.f,0.f,0.f);
    float4 acc3 = make_float4(0.f,0.f,0.f,0.f);

    for (int sc = 0; sc < nsub; ++sc) {
        const int k0 = kt * kchunk + sc * kBK;
        __syncthreads();
        #pragma unroll
        for (int it = 0; it < 8; ++it) {
            const int idx = it * 256 + tid;
            const int m   = idx >> 4;
            const int c4  = idx & 15;
            const float4 v = *(const float4*)(combined + (size_t)m * kH + k0 + c4 * 4);
            At[(c4 * 4 + 0) * 132 + m] = v.x;
            At[(c4 * 4 + 1) * 132 + m] = v.y;
            At[(c4 * 4 + 2) * 132 + m] = v.z;
            At[(c4 * 4 + 3) * 132 + m] = v.w;
        }
        #pragma unroll
        for (int it = 0; it < 2; ++it) {
            const int idx = it * 256 + tid;
            const int kk  = idx >> 3;
            const int cc  = idx & 7;
            *(float4*)(Bs + kk * kBN + cc * 4) =
                *(const float4*)(Wo + (size_t)(k0 + kk) * kH + n0 + cc * 4);
        }
        __syncthreads();
        #pragma unroll 8
        for (int kk = 0; kk < kBK; ++kk) {
            const float4 av = *(const float4*)(At + kk * 132 + mg * 4);
            const float4 bv = *(const float4*)(Bs + kk * kBN + n8 * 4);
            acc0.x = fmaf(av.x, bv.x, acc0.x); acc0.y = fmaf(av.x, bv.y, acc0.y);
            acc0.z = fmaf(av.x, bv.z, acc0.z); acc0.w = fmaf(av.x, bv.w, acc0.w);
            acc1.x = fmaf(av.y, bv.x, acc1.x); acc1.y = fmaf(av.y, bv.y, acc1.y);
            acc1.z = fmaf(av.y, bv.z, acc1.z); acc1.w = fmaf(av.y, bv.w, acc1.w);
            acc2.x = fmaf(av.z, bv.x, acc2.x); acc2.y = fmaf(av.z, bv.y, acc2.y);
            acc2.z = fmaf(av.z, bv.z, acc2.z); acc2.w = fmaf(av.z, bv.w, acc2.w);
            acc3.x = fmaf(av.w, bv.x, acc3.x); acc3.y = fmaf(av.w, bv.y, acc3.y);
            acc3.z = fmaf(av.w, bv.z, acc3.z); acc3.w = fmaf(av.w, bv.w, acc3.w);
        }
    }
    float* base = kpart + ((size_t)kt * kB + mg * 4) * kH + n0 + n8 * 4;
    *(float4*)(base)          = acc0;
    *(float4*)(base + kH)     = acc1;
    *(float4*)(base + 2 * kH) = acc2;
    *(float4*)(base + 3 * kH) = acc3;
}

__global__ __launch_bounds__(256) void k3b_reduce(
    const float* __restrict__ kpart, const float* __restrict__ bo,
    float* __restrict__ out, int KT)
{
    const int g = blockIdx.x * 256 + threadIdx.x;
    const float4* kp = (const float4*)kpart;
    float4 a = make_float4(0.f, 0.f, 0.f, 0.f);
    float4 b = make_float4(0.f, 0.f, 0.f, 0.f);
    float4 cacc = make_float4(0.f, 0.f, 0.f, 0.f);
    float4 d = make_float4(0.f, 0.f, 0.f, 0.f);
    int t = 0;
    for (; t + 3 < KT; t += 4) {
        const float4 v0 = kp[(size_t)(t + 0) * (kB * kH / 4) + g];
        const float4 v1 = kp[(size_t)(t + 1) * (kB * kH / 4) + g];
        const float4 v2 = kp[(size_t)(t + 2) * (kB * kH / 4) + g];
        const float4 v3 = kp[(size_t)(t + 3) * (kB * kH / 4) + g];
        a.x += v0.x; a.y += v0.y; a.z += v0.z; a.w += v0.w;
        b.x += v1.x; b.y += v1.y; b.z += v1.z; b.w += v1.w;
        cacc.x += v2.x; cacc.y += v2.y; cacc.z += v2.z; cacc.w += v2.w;
        d.x += v3.x; d.y += v3.y; d.z += v3.z; d.w += v3.w;
    }
    for (; t < KT; ++t) {
        const float4 v0 = kp[(size_t)t * (kB * kH / 4) + g];
        a.x += v0.x; a.y += v0.y; a.z += v0.z; a.w += v0.w;
    }
    a.x += b.x + cacc.x + d.x;
    a.y += b.y + cacc.y + d.y;
    a.z += b.z + cacc.z + d.z;
    a.w += b.w + cacc.w + d.w;
    const float4 bq = ((const float4*)bo)[g & 255];
    a.x += bq.x; a.y += bq.y; a.z += bq.z; a.w += bq.w;
    ((float4*)out)[g] = a;
}

// ---------------------------------------------------------------------------
extern "C" void kernel_launch(void* const* d_in, const int* in_sizes, int n_in,
                              void* d_out, int out_size, void* d_ws, size_t ws_size,
                              hipStream_t stream) {
    const float* pd   = (const float*)d_in[0];
    const int*   plen = (const int*)  d_in[1];
    const int*   bnum = (const int*)  d_in[2];
    const float* pimg = (const float*)d_in[3];
    const float* W1   = (const float*)d_in[4];
    const float* b1   = (const float*)d_in[5];
    const float* lng  = (const float*)d_in[6];
    const float* lnb  = (const float*)d_in[7];
    const float* W2   = (const float*)d_in[8];
    const float* b2   = (const float*)d_in[9];
    const float* btab = (const float*)d_in[10];
    const float* cw   = (const float*)d_in[11];
    const float* cb   = (const float*)d_in[12];
    const float* Wo   = (const float*)d_in[13];
    const float* bo   = (const float*)d_in[14];
    float* out = (float*)d_out;

    // ---- mega (cooperative) layout: C = 4096 ----
    {
        float* partial  = (float*)d_ws;                     // 4096*256 floats (4MB)
        float* combined = partial + (size_t)kCm * 256;      // 128*1024
        float* Wp       = combined + (size_t)kB * kH;
        float* bpp      = Wp + 768;
        int*   cs_g     = (int*)(bpp + 256);
        int4*  ctab     = (int4*)(cs_g + 132);              // 4096 int4
        float* rstdb    = (float*)(ctab + kCm);             // 128*2048 floats

        void* args[] = {
            (void*)&pd, (void*)&plen, (void*)&bnum, (void*)&pimg,
            (void*)&W1, (void*)&b1, (void*)&lng, (void*)&lnb,
            (void*)&W2, (void*)&b2, (void*)&btab, (void*)&cw, (void*)&cb,
            (void*)&Wo, (void*)&bo, (void*)&out,
            (void*)&partial, (void*)&combined, (void*)&Wp, (void*)&bpp,
            (void*)&cs_g, (void*)&ctab, (void*)&rstdb
        };
        hipError_t err = hipLaunchCooperativeKernel(
            reinterpret_cast<const void*>(&mega_kernel),
            dim3(1024), dim3(256), args, 0, stream);
        if (err == hipSuccess) return;
        (void)hipGetLastError();   // clear sticky error, use fallback
    }

    // ---- fallback: round-9 five-kernel path (proven) ----
    int C = 2048;
    {
        const int Cs[3] = {8192, 4096, 2048};
        for (int i = 0; i < 3; ++i) {
            const size_t need = ((size_t)Cs[i] * 256 + (size_t)kB * kH + 768 + 256 + 132) * 4 +
                                (size_t)Cs[i] * 16 + (size_t)kB * kP * 4 + 256;
            if (ws_size >= need) { C = Cs[i]; break; }
        }
    }
    const int K  = (kB * kP + C - 129) / (C - 128);
    const int KT = C / 512;

    float* partial  = (float*)d_ws;
    float* combined = partial + (size_t)C * 256;
    float* Wp       = combined + (size_t)kB * kH;
    float* bpp      = Wp + 768;
    int*   cs_g     = (int*)(bpp + 256);
    int4*  ctab     = (int4*)(cs_g + 132);
    float* rstdb    = (float*)(ctab + C);
    float* kpart    = partial;

    k0_setup<<<dim3(C / 256 + kRSTD_BLOCKS), 256, 0, stream>>>(
        plen, W1, b1, lng, pd, Wp, bpp, cs_g, ctab, rstdb, C, K);
    k1_pd_partial<<<dim3(C / 4), 256, 0, stream>>>(pd, Wp, bpp, lnb, ctab, rstdb, partial);
    k2_combined<<<dim3(kB, 2), 256, 0, stream>>>(partial, plen, W2, b2, bnum, btab,
                                                 pimg, cw, cb, combined, cs_g);
    k3a_outproj<<<dim3(32, KT), 256, 0, stream>>>(combined, Wo, kpart, KT);
    k3b_reduce<<<dim3(kB), 256, 0, stream>>>(kpart, bo, out, KT);
}

// Round 13
// 58.320 us; speedup vs baseline: 8.0758x; 8.0758x over previous
//
#include <hip/hip_runtime.h>
#include <math.h>

constexpr int kB   = 128;
constexpr int kP   = 2048;
constexpr int kRES = 4096;
constexpr int kF   = 256;
constexpr int kH   = 1024;
constexpr float kLN_EPS = 1e-5f;
constexpr int kBN = 32;   // k3 cols per n-tile
constexpr int kBK = 64;   // k3 K sub-chunk
constexpr int kRSTD_BLOCKS = 512;   // k0 rstd blocks: 512 rows each

#if __has_builtin(__builtin_amdgcn_exp2f)
#define EXP2F __builtin_amdgcn_exp2f
#else
#define EXP2F exp2f
#endif
#if __has_builtin(__builtin_amdgcn_rcpf)
#define RCPF __builtin_amdgcn_rcpf
#else
#define RCPF(x) (1.0f / (x))
#endif

// gelu(y) = 0.5*y*(1+erf(y/sqrt2)); erf via A&S 7.1.25 (3-term, |err|<=2.5e-5).
__device__ __forceinline__ float gelu_fast(float y) {
    const float a = fabsf(y);
    const float t = RCPF(fmaf(0.33267096f, a, 1.0f));
    const float e = EXP2F(-0.72134752f * y * y);
    const float p = fmaf(fmaf(0.37392780f, t, -0.04793990f), t, 0.17401210f);
    const float w = (p * t) * e;
    return fmaf(-a, w, fmaf(0.5f, y, 0.5f * a));
}

__device__ __forceinline__ void build_chain_starts(
    const int* __restrict__ plen, int C, int K, int tid,
    unsigned* s1, unsigned* s2, int* cs)
{
    if (tid < kB) s1[tid] = (unsigned)plen[tid] + (unsigned)K;
    __syncthreads();
    unsigned* src = s1; unsigned* dst = s2;
    #pragma unroll
    for (int d = 1; d < kB; d <<= 1) {
        if (tid < kB) dst[tid] = src[tid] + ((tid >= d) ? src[tid - d] : 0u);
        __syncthreads();
        unsigned* t = src; src = dst; dst = t;
    }
    const unsigned total = src[kB - 1];
    if (tid <= kB) {
        const unsigned pre = (tid == 0) ? 0u : src[tid - 1];
        cs[tid] = (int)(((unsigned long long)pre * (unsigned)C) / total);
    }
    __syncthreads();
}

__device__ __forceinline__ void ln_constants(
    const float* __restrict__ W1, const float* __restrict__ b1,
    int tid, float pr[14][4], float* cl)
{
    const float w0 = W1[tid], w1 = W1[256 + tid], w2 = W1[512 + tid], bb = b1[tid];
    float v[14] = { w0, w1, w2, bb, w0*w0, w0*w1, w0*w2, w1*w1, w1*w2, w2*w2,
                    w0*bb, w1*bb, w2*bb, bb*bb };
    #pragma unroll
    for (int off = 32; off; off >>= 1) {
        #pragma unroll
        for (int i = 0; i < 14; ++i) v[i] += __shfl_xor(v[i], off);
    }
    if ((tid & 63) == 0) {
        #pragma unroll
        for (int i = 0; i < 14; ++i) pr[i][tid >> 6] = v[i];
    }
    __syncthreads();
    if (tid < 14)
        cl[tid] = (pr[tid][0] + pr[tid][1] + pr[tid][2] + pr[tid][3]) * (1.f / 256.f);
    __syncthreads();
}

// ---------------------------------------------------------------------------
// Kernel 0 (round-9 verbatim): setup + per-row rstd precompute.
// ---------------------------------------------------------------------------
__global__ __launch_bounds__(256) void k0_setup(
    const int* __restrict__ plen, const float* __restrict__ W1,
    const float* __restrict__ b1, const float* __restrict__ ln_g,
    const float* __restrict__ pd,
    float* __restrict__ Wp, float* __restrict__ bp,
    int* __restrict__ cs_g, int4* __restrict__ ctab,
    float* __restrict__ rstdb, int C, int K)
{
    __shared__ unsigned s1[kB], s2[kB];
    __shared__ int cs[kB + 1];
    __shared__ float pr[14][4];
    __shared__ float cl[14];
    const int tid = threadIdx.x;
    const int bid = blockIdx.x;
    const int NB_TAB = C >> 8;

    if (bid >= NB_TAB) {
        ln_constants(W1, b1, tid, pr, cl);
        const float S0 = cl[0], S1c = cl[1], S2c = cl[2], Sb = cl[3];
        const float P00 = cl[4], P01 = cl[5], P02 = cl[6];
        const float P11 = cl[7], P12 = cl[8], P22 = cl[9];
        const float Q0 = cl[10], Q1 = cl[11], Q2 = cl[12], Rc = cl[13];
        const int rbase = (bid - NB_TAB) * 512;
        #pragma unroll
        for (int u = 0; u < 2; ++u) {
            const int r = rbase + u * 256 + tid;
            const float* rp = pd + (size_t)r * 3;
            const float x0 = rp[0], x1 = rp[1], x2 = rp[2];
            const float mu = fmaf(x2, S2c, fmaf(x1, S1c, fmaf(x0, S0, Sb)));
            const float sx = fmaf(P01 * x0, x1, fmaf(P02 * x0, x2, fmaf(P12 * x1, x2,
                             fmaf(Q0, x0, fmaf(Q1, x1, Q2 * x2)))));
            const float e2 = fmaf(P00 * x0, x0, fmaf(P11 * x1, x1, fmaf(P22 * x2, x2,
                             fmaf(2.f, sx, Rc))));
            rstdb[r] = rsqrtf(fmaf(-mu, mu, e2) + kLN_EPS);
        }
        return;
    }

    build_chain_starts(plen, C, K, tid, s1, s2, cs);
    const int c = bid * 256 + tid;
    {
        int lo = 0, hi = kB;
        while (hi - lo > 1) { const int mid = (lo + hi) >> 1; if (cs[mid] <= c) lo = mid; else hi = mid; }
        const int b = lo;
        const int m = cs[b + 1] - cs[b];
        const int j = c - cs[b];
        const int len = plen[b];
        const int T  = (len + 3) >> 2;
        const int l4 = (int)(((long long)j * T) / m);
        const int h4 = (int)(((long long)(j + 1) * T) / m);
        const int start = min(l4 * 4, len);
        const int cnt   = max(0, min(h4 * 4, len) - start);
        ctab[c] = make_int4(b, start, cnt, 0);
    }
    if (bid == 0) {
        if (tid <= kB) cs_g[tid] = cs[tid];
        ln_constants(W1, b1, tid, pr, cl);
        const float g = ln_g[tid];
        Wp[tid]       = (W1[tid]       - cl[0]) * g;
        Wp[256 + tid] = (W1[256 + tid] - cl[1]) * g;
        Wp[512 + tid] = (W1[512 + tid] - cl[2]) * g;
        bp[tid]       = (b1[tid]       - cl[3]) * g;
    }
}

// ---------------------------------------------------------------------------
// Kernel 1 (round-9 verbatim): grid = C/4 x 256.
// ---------------------------------------------------------------------------
__global__ __launch_bounds__(256) void k1_pd_partial(
    const float* __restrict__ pd, const float* __restrict__ Wp,
    const float* __restrict__ bp, const float* __restrict__ ln_b,
    const int4* __restrict__ ctab, const float* __restrict__ rstdb,
    float* __restrict__ partial)
{
    const int tid = threadIdx.x, lane = tid & 63, wave = tid >> 6;
    const int c = blockIdx.x * 4 + wave;
    const int4 ci = ctab[c];
    const int b = ci.x, start = ci.y, cnt = ci.z;

    const float4 w0q = ((const float4*)Wp)[lane];
    const float4 w1q = ((const float4*)Wp)[64 + lane];
    const float4 w2q = ((const float4*)Wp)[128 + lane];
    const float4 bpq = ((const float4*)bp)[lane];
    const float4 beq = ((const float4*)ln_b)[lane];

    float a0 = 0.f, a1 = 0.f, a2 = 0.f, a3 = 0.f;

#define ROW(x0, x1, x2, rs)                                                      \
    {                                                                            \
        const float h0 = fmaf((x2), w2q.x, fmaf((x1), w1q.x, fmaf((x0), w0q.x, bpq.x))); \
        const float h1 = fmaf((x2), w2q.y, fmaf((x1), w1q.y, fmaf((x0), w0q.y, bpq.y))); \
        const float h2 = fmaf((x2), w2q.z, fmaf((x1), w1q.z, fmaf((x0), w0q.z, bpq.z))); \
        const float h3 = fmaf((x2), w2q.w, fmaf((x1), w1q.w, fmaf((x0), w0q.w, bpq.w))); \
        a0 += gelu_fast(fmaf(h0, (rs), beq.x));                                  \
        a1 += gelu_fast(fmaf(h1, (rs), beq.y));                                  \
        a2 += gelu_fast(fmaf(h2, (rs), beq.z));                                  \
        a3 += gelu_fast(fmaf(h3, (rs), beq.w));                                  \
    }

    const int nq  = cnt >> 2;
    const int rem = cnt & 3;
    const float4* qp = (const float4*)(pd + ((size_t)b * kP + start) * 3);
    const float4* rs4 = (const float4*)(rstdb + (size_t)b * kP + start);
    for (int it = 0; it < nq; ++it) {
        const float4 f0 = qp[0];
        const float4 f1 = qp[1];
        const float4 f2 = qp[2];
        const float4 rq = rs4[it];
        qp += 3;
        ROW(f0.x, f0.y, f0.z, rq.x);
        ROW(f0.w, f1.x, f1.y, rq.y);
        ROW(f1.z, f1.w, f2.x, rq.z);
        ROW(f2.y, f2.z, f2.w, rq.w);
    }
    const float* rp = (const float*)qp;
    const float* rsp = rstdb + (size_t)b * kP + start + nq * 4;
    for (int it = 0; it < rem; ++it, rp += 3) {
        ROW(rp[0], rp[1], rp[2], rsp[it]);
    }
#undef ROW

    ((float4*)(partial + ((size_t)c << 8)))[lane] = make_float4(a0, a1, a2, a3);
}

// ---------------------------------------------------------------------------
// Kernel 2 (round-9 + out-init): combined[b][1024]. grid (kB, 2) x 256.
// Also writes out[b] = bo (the k3 atomic epilogue accumulates on top).
// ---------------------------------------------------------------------------
__global__ __launch_bounds__(256) void k2_combined(
    const float* __restrict__ partial, const int* __restrict__ plen,
    const float* __restrict__ W2, const float* __restrict__ b2,
    const int* __restrict__ betti, const float* __restrict__ betti_table,
    const float* __restrict__ pimg, const float* __restrict__ conv_w,
    const float* __restrict__ conv_b, float* __restrict__ combined,
    const int* __restrict__ cs_g, const float* __restrict__ bo,
    float* __restrict__ out)
{
    __shared__ float red[4 * 256];
    __shared__ float ml[256];
    __shared__ float sred[2][4];
    const int b    = blockIdx.x;
    const int tid  = threadIdx.x;
    const int wave = tid >> 6;
    const int lane = tid & 63;

    // out init: block q covers float4 idx [q*128, q*128+128) of row b
    if (tid < 128) {
        const int f4 = blockIdx.y * 128 + tid;
        ((float4*)(out + (size_t)b * kH))[f4] = ((const float4*)bo)[f4];
    }

    if (blockIdx.y == 0) {
        const int len = plen[b];
        const int c0 = cs_g[b], c1 = cs_g[b + 1];

        float4 aq = make_float4(0.f, 0.f, 0.f, 0.f);
        float4 bq = make_float4(0.f, 0.f, 0.f, 0.f);
        int c = c0 + wave;
        for (; c + 4 < c1; c += 8) {
            const float4 v0 = ((const float4*)(partial + ((size_t)c << 8)))[lane];
            const float4 v1 = ((const float4*)(partial + ((size_t)(c + 4) << 8)))[lane];
            aq.x += v0.x; aq.y += v0.y; aq.z += v0.z; aq.w += v0.w;
            bq.x += v1.x; bq.y += v1.y; bq.z += v1.z; bq.w += v1.w;
        }
        if (c < c1) {
            const float4 v0 = ((const float4*)(partial + ((size_t)c << 8)))[lane];
            aq.x += v0.x; aq.y += v0.y; aq.z += v0.z; aq.w += v0.w;
        }
        aq.x += bq.x; aq.y += bq.y; aq.z += bq.z; aq.w += bq.w;
        ((float4*)red)[wave * 64 + lane] = aq;
        __syncthreads();
        const float inv = (len > 0) ? (1.f / (float)len) : 0.f;
        ml[tid] = (red[tid] + red[256 + tid] + red[512 + tid] + red[768 + tid]) * inv;
        __syncthreads();

        const float4* W24 = (const float4*)W2;
        float4 acc = make_float4(0.f, 0.f, 0.f, 0.f);
        const int f0 = wave * 64;
        #pragma unroll 8
        for (int i = 0; i < 64; ++i) {
            const float mv = ml[f0 + i];
            const float4 wv = W24[(size_t)(f0 + i) * 64 + lane];
            acc.x = fmaf(mv, wv.x, acc.x); acc.y = fmaf(mv, wv.y, acc.y);
            acc.z = fmaf(mv, wv.z, acc.z); acc.w = fmaf(mv, wv.w, acc.w);
        }
        ((float4*)red)[wave * 64 + lane] = acc;
        __syncthreads();
        const float o = (red[tid] + red[256 + tid]) + (red[512 + tid] + red[768 + tid]);
        combined[(size_t)b * kH + tid] = (len > 0) ? (o + b2[tid]) : 0.f;

        const int i0 = min(max(betti[b * 3 + 0], 0), 9);
        const int i1 = min(max(betti[b * 3 + 1], 0), 9);
        const int i2 = min(max(betti[b * 3 + 2], 0), 9);
        combined[(size_t)b * kH + 256 + tid] =
            (betti_table[i0 * 256 + tid] + betti_table[i1 * 256 + tid] +
             betti_table[i2 * 256 + tid]) * (1.f / 3.f);
    } else {
        const float4* x4 = (const float4*)(pimg + (size_t)b * kRES);
        float se = 0.f, so = 0.f;
        #pragma unroll
        for (int j = 0; j < 4; ++j) {
            const float4 v = x4[tid + j * 256];
            se += v.x + v.z;
            so += v.y + v.w;
        }
        #pragma unroll
        for (int off = 32; off; off >>= 1) {
            se += __shfl_xor(se, off);
            so += __shfl_xor(so, off);
        }
        if (lane == 0) { sred[0][wave] = se; sred[1][wave] = so; }
        __syncthreads();
        se = (sred[0][0] + sred[0][1]) + (sred[0][2] + sred[0][3]);
        so = (sred[1][0] + sred[1][1]) + (sred[1][2] + sred[1][3]);

        const float x0 = pimg[(size_t)b * kRES + 0];
        const float xe = pimg[(size_t)b * kRES + 4094];
        const float xo = pimg[(size_t)b * kRES + 4095];
        #pragma unroll
        for (int u = 0; u < 2; ++u) {
            const int cc = tid + u * 256;
            const float* w = conv_w + (size_t)cc * 5;
            const float v = w[0] * (se - xe) + w[1] * (so - xo) + w[2] * se +
                            w[3] * so + w[4] * (se - x0);
            combined[(size_t)b * kH + 512 + cc] = v * (1.f / 2048.f) + conv_b[cc];
        }
    }
}

// ---------------------------------------------------------------------------
// Kernel 3 (atomic epilogue): split-K GEMM, zero Wo redundancy, accumulates
// directly into out (pre-initialized with bo by k2). grid (32 nt, KT kt).
// ---------------------------------------------------------------------------
__global__ __launch_bounds__(256) void k3_atomic(
    const float* __restrict__ combined, const float* __restrict__ Wo,
    float* __restrict__ out, int KT)
{
    const int nt  = blockIdx.x;
    const int kt  = blockIdx.y;
    const int tid = threadIdx.x;
    const int n0  = nt * kBN;
    const int kchunk = kH / KT;
    const int nsub   = kchunk / kBK;

    __shared__ float At[kBK * 132];
    __shared__ float Bs[kBK * kBN];

    const int n8 = tid & 7;
    const int mg = tid >> 3;

    float4 acc0 = make_float4(0.f,0.f,0.f,0.f);
    float4 acc1 = make_float4(0.f,0.f,0.f,0.f);
    float4 acc2 = make_float4(0.f,0.f,0.f,0.f);
    float4 acc3 = make_float4(0.f,0.f,0.f,0.f);

    for (int sc = 0; sc < nsub; ++sc) {
        const int k0 = kt * kchunk + sc * kBK;
        __syncthreads();
        #pragma unroll
        for (int it = 0; it < 8; ++it) {
            const int idx = it * 256 + tid;
            const int m   = idx >> 4;
            const int c4  = idx & 15;
            const float4 v = *(const float4*)(combined + (size_t)m * kH + k0 + c4 * 4);
            At[(c4 * 4 + 0) * 132 + m] = v.x;
            At[(c4 * 4 + 1) * 132 + m] = v.y;
            At[(c4 * 4 + 2) * 132 + m] = v.z;
            At[(c4 * 4 + 3) * 132 + m] = v.w;
        }
        #pragma unroll
        for (int it = 0; it < 2; ++it) {
            const int idx = it * 256 + tid;
            const int kk  = idx >> 3;
            const int cc  = idx & 7;
            *(float4*)(Bs + kk * kBN + cc * 4) =
                *(const float4*)(Wo + (size_t)(k0 + kk) * kH + n0 + cc * 4);
        }
        __syncthreads();

        #pragma unroll 8
        for (int kk = 0; kk < kBK; ++kk) {
            const float4 av = *(const float4*)(At + kk * 132 + mg * 4);
            const float4 bv = *(const float4*)(Bs + kk * kBN + n8 * 4);
            acc0.x = fmaf(av.x, bv.x, acc0.x); acc0.y = fmaf(av.x, bv.y, acc0.y);
            acc0.z = fmaf(av.x, bv.z, acc0.z); acc0.w = fmaf(av.x, bv.w, acc0.w);
            acc1.x = fmaf(av.y, bv.x, acc1.x); acc1.y = fmaf(av.y, bv.y, acc1.y);
            acc1.z = fmaf(av.y, bv.z, acc1.z); acc1.w = fmaf(av.y, bv.w, acc1.w);
            acc2.x = fmaf(av.z, bv.x, acc2.x); acc2.y = fmaf(av.z, bv.y, acc2.y);
            acc2.z = fmaf(av.z, bv.z, acc2.z); acc2.w = fmaf(av.z, bv.w, acc2.w);
            acc3.x = fmaf(av.w, bv.x, acc3.x); acc3.y = fmaf(av.w, bv.y, acc3.y);
            acc3.z = fmaf(av.w, bv.z, acc3.z); acc3.w = fmaf(av.w, bv.w, acc3.w);
        }
    }

    float* base = out + ((size_t)mg * 4) * kH + n0 + n8 * 4;
    atomicAdd(base + 0,          acc0.x); atomicAdd(base + 1,          acc0.y);
    atomicAdd(base + 2,          acc0.z); atomicAdd(base + 3,          acc0.w);
    atomicAdd(base + kH + 0,     acc1.x); atomicAdd(base + kH + 1,     acc1.y);
    atomicAdd(base + kH + 2,     acc1.z); atomicAdd(base + kH + 3,     acc1.w);
    atomicAdd(base + 2*kH + 0,   acc2.x); atomicAdd(base + 2*kH + 1,   acc2.y);
    atomicAdd(base + 2*kH + 2,   acc2.z); atomicAdd(base + 2*kH + 3,   acc2.w);
    atomicAdd(base + 3*kH + 0,   acc3.x); atomicAdd(base + 3*kH + 1,   acc3.y);
    atomicAdd(base + 3*kH + 2,   acc3.z); atomicAdd(base + 3*kH + 3,   acc3.w);
}

// ---------------------------------------------------------------------------
extern "C" void kernel_launch(void* const* d_in, const int* in_sizes, int n_in,
                              void* d_out, int out_size, void* d_ws, size_t ws_size,
                              hipStream_t stream) {
    const float* pd   = (const float*)d_in[0];
    const int*   plen = (const int*)  d_in[1];
    const int*   bnum = (const int*)  d_in[2];
    const float* pimg = (const float*)d_in[3];
    const float* W1   = (const float*)d_in[4];
    const float* b1   = (const float*)d_in[5];
    const float* lng  = (const float*)d_in[6];
    const float* lnb  = (const float*)d_in[7];
    const float* W2   = (const float*)d_in[8];
    const float* b2   = (const float*)d_in[9];
    const float* btab = (const float*)d_in[10];
    const float* cw   = (const float*)d_in[11];
    const float* cb   = (const float*)d_in[12];
    const float* Wo   = (const float*)d_in[13];
    const float* bo   = (const float*)d_in[14];
    float* out = (float*)d_out;

    int C = 2048;
    {
        const int Cs[2] = {4096, 2048};
        for (int i = 0; i < 2; ++i) {
            const size_t need = ((size_t)Cs[i] * 256 + (size_t)kB * kH + 768 + 256 + 132) * 4 +
                                (size_t)Cs[i] * 16 + (size_t)kB * kP * 4 + 256;
            if (ws_size >= need) { C = Cs[i]; break; }
        }
    }
    const int K  = (kB * kP + C - 129) / (C - 128);  // >=1 chain per batch
    const int KT = C / 512;                          // 8 or 4

    float* partial  = (float*)d_ws;                  // C*256 floats
    float* combined = partial + (size_t)C * 256;     // 128*1024 floats
    float* Wp       = combined + (size_t)kB * kH;    // 768 floats
    float* bpp      = Wp + 768;                      // 256 floats
    int*   cs_g     = (int*)(bpp + 256);             // 132 ints
    int4*  ctab     = (int4*)(cs_g + 132);           // C int4 (16B-aligned)
    float* rstdb    = (float*)(ctab + C);            // 128*2048 floats (1 MB)

    k0_setup<<<dim3(C / 256 + kRSTD_BLOCKS), 256, 0, stream>>>(
        plen, W1, b1, lng, pd, Wp, bpp, cs_g, ctab, rstdb, C, K);
    k1_pd_partial<<<dim3(C / 4), 256, 0, stream>>>(pd, Wp, bpp, lnb, ctab, rstdb, partial);
    k2_combined<<<dim3(kB, 2), 256, 0, stream>>>(partial, plen, W2, b2, bnum, btab,
                                                 pimg, cw, cb, combined, cs_g, bo, out);
    k3_atomic<<<dim3(32, KT), 256, 0, stream>>>(combined, Wo, out, KT);
}

// Round 14
// 52.344 us; speedup vs baseline: 8.9978x; 1.1142x over previous
//
#include <hip/hip_runtime.h>
#include <math.h>

constexpr int kB   = 128;
constexpr int kP   = 2048;
constexpr int kRES = 4096;
constexpr int kF   = 256;
constexpr int kH   = 1024;
constexpr float kLN_EPS = 1e-5f;
constexpr int kBN = 32;   // k3 cols per n-tile
constexpr int kBK = 64;   // k3 K sub-chunk
constexpr int kRSTD_BLOCKS = 512;   // k0 rstd blocks: 512 rows each

#if __has_builtin(__builtin_amdgcn_exp2f)
#define EXP2F __builtin_amdgcn_exp2f
#else
#define EXP2F exp2f
#endif
#if __has_builtin(__builtin_amdgcn_rcpf)
#define RCPF __builtin_amdgcn_rcpf
#else
#define RCPF(x) (1.0f / (x))
#endif

// gelu(y) = 0.5*y*(1+erf(y/sqrt2)); erf via A&S 7.1.25 (3-term, |err|<=2.5e-5).
__device__ __forceinline__ float gelu_fast(float y) {
    const float a = fabsf(y);
    const float t = RCPF(fmaf(0.33267096f, a, 1.0f));       // 1/(1 + p*a/sqrt2)
    const float e = EXP2F(-0.72134752f * y * y);            // exp(-y^2/2)
    const float p = fmaf(fmaf(0.37392780f, t, -0.04793990f), t, 0.17401210f);
    const float w = (p * t) * e;                            // 0.5*erfc(a/sqrt2)
    return fmaf(-a, w, fmaf(0.5f, y, 0.5f * a));
}

// Proportional chain-start table cs[0..128] in LDS (prefix scan of len+K).
__device__ __forceinline__ void build_chain_starts(
    const int* __restrict__ plen, int C, int K, int tid,
    unsigned* s1, unsigned* s2, int* cs)
{
    if (tid < kB) s1[tid] = (unsigned)plen[tid] + (unsigned)K;
    __syncthreads();
    unsigned* src = s1; unsigned* dst = s2;
    #pragma unroll
    for (int d = 1; d < kB; d <<= 1) {
        if (tid < kB) dst[tid] = src[tid] + ((tid >= d) ? src[tid - d] : 0u);
        __syncthreads();
        unsigned* t = src; src = dst; dst = t;
    }
    const unsigned total = src[kB - 1];
    if (tid <= kB) {
        const unsigned pre = (tid == 0) ? 0u : src[tid - 1];
        cs[tid] = (int)(((unsigned long long)pre * (unsigned)C) / total);
    }
    __syncthreads();
}

// 14 feature-mean constants via 256-thread reduce. Leaves results in cl[14].
__device__ __forceinline__ void ln_constants(
    const float* __restrict__ W1, const float* __restrict__ b1,
    int tid, float pr[14][4], float* cl)
{
    const float w0 = W1[tid], w1 = W1[256 + tid], w2 = W1[512 + tid], bb = b1[tid];
    float v[14] = { w0, w1, w2, bb, w0*w0, w0*w1, w0*w2, w1*w1, w1*w2, w2*w2,
                    w0*bb, w1*bb, w2*bb, bb*bb };
    #pragma unroll
    for (int off = 32; off; off >>= 1) {
        #pragma unroll
        for (int i = 0; i < 14; ++i) v[i] += __shfl_xor(v[i], off);
    }
    if ((tid & 63) == 0) {
        #pragma unroll
        for (int i = 0; i < 14; ++i) pr[i][tid >> 6] = v[i];
    }
    __syncthreads();
    if (tid < 14)
        cl[tid] = (pr[tid][0] + pr[tid][1] + pr[tid][2] + pr[tid][3]) * (1.f / 256.f);
    __syncthreads();
}

// ---------------------------------------------------------------------------
// Kernel 0: setup + per-row rstd precompute. grid = C/256 + 512 blocks.
//  - blocks [0, C/256): quad-aligned ctab entries; block 0 also writes cs_g
//    and folded weights Wp=(W1-S)*g, bp=(b1-Sb)*g.
//  - blocks [C/256, +512): rstd[row] for all 262144 rows (lane-parallel).
// ---------------------------------------------------------------------------
__global__ __launch_bounds__(256) void k0_setup(
    const int* __restrict__ plen, const float* __restrict__ W1,
    const float* __restrict__ b1, const float* __restrict__ ln_g,
    const float* __restrict__ pd,
    float* __restrict__ Wp, float* __restrict__ bp,
    int* __restrict__ cs_g, int4* __restrict__ ctab,
    float* __restrict__ rstdb, int C, int K)
{
    __shared__ unsigned s1[kB], s2[kB];
    __shared__ int cs[kB + 1];
    __shared__ float pr[14][4];
    __shared__ float cl[14];
    const int tid = threadIdx.x;
    const int bid = blockIdx.x;
    const int NB_TAB = C >> 8;

    if (bid >= NB_TAB) {
        // --- rstd pass ---
        ln_constants(W1, b1, tid, pr, cl);
        const float S0 = cl[0], S1c = cl[1], S2c = cl[2], Sb = cl[3];
        const float P00 = cl[4], P01 = cl[5], P02 = cl[6];
        const float P11 = cl[7], P12 = cl[8], P22 = cl[9];
        const float Q0 = cl[10], Q1 = cl[11], Q2 = cl[12], Rc = cl[13];
        const int rbase = (bid - NB_TAB) * 512;
        #pragma unroll
        for (int u = 0; u < 2; ++u) {
            const int r = rbase + u * 256 + tid;
            const float* rp = pd + (size_t)r * 3;
            const float x0 = rp[0], x1 = rp[1], x2 = rp[2];
            const float mu = fmaf(x2, S2c, fmaf(x1, S1c, fmaf(x0, S0, Sb)));
            const float sx = fmaf(P01 * x0, x1, fmaf(P02 * x0, x2, fmaf(P12 * x1, x2,
                             fmaf(Q0, x0, fmaf(Q1, x1, Q2 * x2)))));
            const float e2 = fmaf(P00 * x0, x0, fmaf(P11 * x1, x1, fmaf(P22 * x2, x2,
                             fmaf(2.f, sx, Rc))));
            rstdb[r] = rsqrtf(fmaf(-mu, mu, e2) + kLN_EPS);
        }
        return;
    }

    // --- table pass ---
    build_chain_starts(plen, C, K, tid, s1, s2, cs);

    const int c = bid * 256 + tid;
    {
        int lo = 0, hi = kB;
        while (hi - lo > 1) { const int mid = (lo + hi) >> 1; if (cs[mid] <= c) lo = mid; else hi = mid; }
        const int b = lo;
        const int m = cs[b + 1] - cs[b];
        const int j = c - cs[b];
        const int len = plen[b];
        const int T  = (len + 3) >> 2;                       // row-quads
        const int l4 = (int)(((long long)j * T) / m);
        const int h4 = (int)(((long long)(j + 1) * T) / m);
        const int start = min(l4 * 4, len);
        const int cnt   = max(0, min(h4 * 4, len) - start);
        ctab[c] = make_int4(b, start, cnt, 0);
    }

    if (bid == 0) {
        if (tid <= kB) cs_g[tid] = cs[tid];
        ln_constants(W1, b1, tid, pr, cl);
        const float g = ln_g[tid];
        Wp[tid]       = (W1[tid]       - cl[0]) * g;
        Wp[256 + tid] = (W1[256 + tid] - cl[1]) * g;
        Wp[512 + tid] = (W1[512 + tid] - cl[2]) * g;
        bp[tid]       = (b1[tid]       - cl[3]) * g;
    }
}

// ---------------------------------------------------------------------------
// Kernel 1: grid = C/4 x 256. Per quad: 3 float4 pd + 1 float4 rstd;
// row body = 16 FMA + 4 gelu (no per-row scalar chain, no rsqrt).
// ---------------------------------------------------------------------------
__global__ __launch_bounds__(256) void k1_pd_partial(
    const float* __restrict__ pd, const float* __restrict__ Wp,
    const float* __restrict__ bp, const float* __restrict__ ln_b,
    const int4* __restrict__ ctab, const float* __restrict__ rstdb,
    float* __restrict__ partial)
{
    const int tid = threadIdx.x, lane = tid & 63, wave = tid >> 6;
    const int c = blockIdx.x * 4 + wave;
    const int4 ci = ctab[c];
    const int b = ci.x, start = ci.y, cnt = ci.z;

    const float4 w0q = ((const float4*)Wp)[lane];
    const float4 w1q = ((const float4*)Wp)[64 + lane];
    const float4 w2q = ((const float4*)Wp)[128 + lane];
    const float4 bpq = ((const float4*)bp)[lane];
    const float4 beq = ((const float4*)ln_b)[lane];

    float a0 = 0.f, a1 = 0.f, a2 = 0.f, a3 = 0.f;

#define ROW(x0, x1, x2, rs)                                                      \
    {                                                                            \
        const float h0 = fmaf((x2), w2q.x, fmaf((x1), w1q.x, fmaf((x0), w0q.x, bpq.x))); \
        const float h1 = fmaf((x2), w2q.y, fmaf((x1), w1q.y, fmaf((x0), w0q.y, bpq.y))); \
        const float h2 = fmaf((x2), w2q.z, fmaf((x1), w1q.z, fmaf((x0), w0q.z, bpq.z))); \
        const float h3 = fmaf((x2), w2q.w, fmaf((x1), w1q.w, fmaf((x0), w0q.w, bpq.w))); \
        a0 += gelu_fast(fmaf(h0, (rs), beq.x));                                  \
        a1 += gelu_fast(fmaf(h1, (rs), beq.y));                                  \
        a2 += gelu_fast(fmaf(h2, (rs), beq.z));                                  \
        a3 += gelu_fast(fmaf(h3, (rs), beq.w));                                  \
    }

    const int nq  = cnt >> 2;
    const int rem = cnt & 3;
    const float4* qp = (const float4*)(pd + ((size_t)b * kP + start) * 3);
    const float4* rs4 = (const float4*)(rstdb + (size_t)b * kP + start);
    for (int it = 0; it < nq; ++it) {
        const float4 f0 = qp[0];
        const float4 f1 = qp[1];
        const float4 f2 = qp[2];
        const float4 rq = rs4[it];
        qp += 3;
        ROW(f0.x, f0.y, f0.z, rq.x);
        ROW(f0.w, f1.x, f1.y, rq.y);
        ROW(f1.z, f1.w, f2.x, rq.z);
        ROW(f2.y, f2.z, f2.w, rq.w);
    }
    const float* rp = (const float*)qp;
    const float* rsp = rstdb + (size_t)b * kP + start + nq * 4;
    for (int it = 0; it < rem; ++it, rp += 3) {
        ROW(rp[0], rp[1], rp[2], rsp[it]);
    }
#undef ROW

    ((float4*)(partial + ((size_t)c << 8)))[lane] = make_float4(a0, a1, a2, a3);
}

// ---------------------------------------------------------------------------
// Kernel 2: combined[b][1024]. grid (kB, 2) x 256. Unrolled chain-sum with
// dual accumulators.
// ---------------------------------------------------------------------------
__global__ __launch_bounds__(256) void k2_combined(
    const float* __restrict__ partial, const int* __restrict__ plen,
    const float* __restrict__ W2, const float* __restrict__ b2,
    const int* __restrict__ betti, const float* __restrict__ betti_table,
    const float* __restrict__ pimg, const float* __restrict__ conv_w,
    const float* __restrict__ conv_b, float* __restrict__ combined,
    const int* __restrict__ cs_g)
{
    __shared__ float red[4 * 256];
    __shared__ float ml[256];
    __shared__ float sred[2][4];
    const int b    = blockIdx.x;
    const int tid  = threadIdx.x;
    const int wave = tid >> 6;
    const int lane = tid & 63;

    if (blockIdx.y == 0) {
        const int len = plen[b];
        const int c0 = cs_g[b], c1 = cs_g[b + 1];

        float4 aq = make_float4(0.f, 0.f, 0.f, 0.f);
        float4 bq = make_float4(0.f, 0.f, 0.f, 0.f);
        int c = c0 + wave;
        for (; c + 4 < c1; c += 8) {
            const float4 v0 = ((const float4*)(partial + ((size_t)c << 8)))[lane];
            const float4 v1 = ((const float4*)(partial + ((size_t)(c + 4) << 8)))[lane];
            aq.x += v0.x; aq.y += v0.y; aq.z += v0.z; aq.w += v0.w;
            bq.x += v1.x; bq.y += v1.y; bq.z += v1.z; bq.w += v1.w;
        }
        if (c < c1) {
            const float4 v0 = ((const float4*)(partial + ((size_t)c << 8)))[lane];
            aq.x += v0.x; aq.y += v0.y; aq.z += v0.z; aq.w += v0.w;
        }
        aq.x += bq.x; aq.y += bq.y; aq.z += bq.z; aq.w += bq.w;
        ((float4*)red)[wave * 64 + lane] = aq;
        __syncthreads();
        const float inv = (len > 0) ? (1.f / (float)len) : 0.f;
        ml[tid] = (red[tid] + red[256 + tid] + red[512 + tid] + red[768 + tid]) * inv;
        __syncthreads();

        const float4* W24 = (const float4*)W2;
        float4 acc = make_float4(0.f, 0.f, 0.f, 0.f);
        const int f0 = wave * 64;
        #pragma unroll 8
        for (int i = 0; i < 64; ++i) {
            const float mv = ml[f0 + i];
            const float4 wv = W24[(size_t)(f0 + i) * 64 + lane];
            acc.x = fmaf(mv, wv.x, acc.x); acc.y = fmaf(mv, wv.y, acc.y);
            acc.z = fmaf(mv, wv.z, acc.z); acc.w = fmaf(mv, wv.w, acc.w);
        }
        ((float4*)red)[wave * 64 + lane] = acc;
        __syncthreads();
        const float o = (red[tid] + red[256 + tid]) + (red[512 + tid] + red[768 + tid]);
        combined[(size_t)b * kH + tid] = (len > 0) ? (o + b2[tid]) : 0.f;

        const int i0 = min(max(betti[b * 3 + 0], 0), 9);
        const int i1 = min(max(betti[b * 3 + 1], 0), 9);
        const int i2 = min(max(betti[b * 3 + 2], 0), 9);
        combined[(size_t)b * kH + 256 + tid] =
            (betti_table[i0 * 256 + tid] + betti_table[i1 * 256 + tid] +
             betti_table[i2 * 256 + tid]) * (1.f / 3.f);
    } else {
        const float4* x4 = (const float4*)(pimg + (size_t)b * kRES);
        float se = 0.f, so = 0.f;
        #pragma unroll
        for (int j = 0; j < 4; ++j) {
            const float4 v = x4[tid + j * 256];
            se += v.x + v.z;
            so += v.y + v.w;
        }
        #pragma unroll
        for (int off = 32; off; off >>= 1) {
            se += __shfl_xor(se, off);
            so += __shfl_xor(so, off);
        }
        if (lane == 0) { sred[0][wave] = se; sred[1][wave] = so; }
        __syncthreads();
        se = (sred[0][0] + sred[0][1]) + (sred[0][2] + sred[0][3]);
        so = (sred[1][0] + sred[1][1]) + (sred[1][2] + sred[1][3]);

        const float x0 = pimg[(size_t)b * kRES + 0];
        const float xe = pimg[(size_t)b * kRES + 4094];
        const float xo = pimg[(size_t)b * kRES + 4095];
        #pragma unroll
        for (int u = 0; u < 2; ++u) {
            const int cc = tid + u * 256;
            const float* w = conv_w + (size_t)cc * 5;
            const float v = w[0] * (se - xe) + w[1] * (so - xo) + w[2] * se +
                            w[3] * so + w[4] * (se - x0);
            combined[(size_t)b * kH + 512 + cc] = v * (1.f / 2048.f) + conv_b[cc];
        }
    }
}

// ---------------------------------------------------------------------------
// Kernel 3a: split-K GEMM, zero Wo redundancy. grid (32 nt, KT kt) x 256.
// ---------------------------------------------------------------------------
__global__ __launch_bounds__(256) void k3a_outproj(
    const float* __restrict__ combined, const float* __restrict__ Wo,
    float* __restrict__ kpart, int KT)
{
    const int nt  = blockIdx.x;
    const int kt  = blockIdx.y;
    const int tid = threadIdx.x;
    const int n0  = nt * kBN;
    const int kchunk = kH / KT;
    const int nsub   = kchunk / kBK;

    __shared__ float At[kBK * 132];
    __shared__ float Bs[kBK * kBN];

    const int n8 = tid & 7;
    const int mg = tid >> 3;

    float4 acc0 = make_float4(0.f,0.f,0.f,0.f);
    float4 acc1 = make_float4(0.f,0.f,0.f,0.f);
    float4 acc2 = make_float4(0.f,0.f,0.f,0.f);
    float4 acc3 = make_float4(0.f,0.f,0.f,0.f);

    for (int sc = 0; sc < nsub; ++sc) {
        const int k0 = kt * kchunk + sc * kBK;
        __syncthreads();
        #pragma unroll
        for (int it = 0; it < 8; ++it) {
            const int idx = it * 256 + tid;
            const int m   = idx >> 4;
            const int c4  = idx & 15;
            const float4 v = *(const float4*)(combined + (size_t)m * kH + k0 + c4 * 4);
            At[(c4 * 4 + 0) * 132 + m] = v.x;
            At[(c4 * 4 + 1) * 132 + m] = v.y;
            At[(c4 * 4 + 2) * 132 + m] = v.z;
            At[(c4 * 4 + 3) * 132 + m] = v.w;
        }
        #pragma unroll
        for (int it = 0; it < 2; ++it) {
            const int idx = it * 256 + tid;
            const int kk  = idx >> 3;
            const int cc  = idx & 7;
            *(float4*)(Bs + kk * kBN + cc * 4) =
                *(const float4*)(Wo + (size_t)(k0 + kk) * kH + n0 + cc * 4);
        }
        __syncthreads();

        #pragma unroll 8
        for (int kk = 0; kk < kBK; ++kk) {
            const float4 av = *(const float4*)(At + kk * 132 + mg * 4);
            const float4 bv = *(const float4*)(Bs + kk * kBN + n8 * 4);
            acc0.x = fmaf(av.x, bv.x, acc0.x); acc0.y = fmaf(av.x, bv.y, acc0.y);
            acc0.z = fmaf(av.x, bv.z, acc0.z); acc0.w = fmaf(av.x, bv.w, acc0.w);
            acc1.x = fmaf(av.y, bv.x, acc1.x); acc1.y = fmaf(av.y, bv.y, acc1.y);
            acc1.z = fmaf(av.y, bv.z, acc1.z); acc1.w = fmaf(av.y, bv.w, acc1.w);
            acc2.x = fmaf(av.z, bv.x, acc2.x); acc2.y = fmaf(av.z, bv.y, acc2.y);
            acc2.z = fmaf(av.z, bv.z, acc2.z); acc2.w = fmaf(av.z, bv.w, acc2.w);
            acc3.x = fmaf(av.w, bv.x, acc3.x); acc3.y = fmaf(av.w, bv.y, acc3.y);
            acc3.z = fmaf(av.w, bv.z, acc3.z); acc3.w = fmaf(av.w, bv.w, acc3.w);
        }
    }

    float* base = kpart + ((size_t)kt * kB + mg * 4) * kH + n0 + n8 * 4;
    *(float4*)(base)          = acc0;
    *(float4*)(base + kH)     = acc1;
    *(float4*)(base + 2 * kH) = acc2;
    *(float4*)(base + 3 * kH) = acc3;
}

// k3b: out = sum_kt kpart + bo. grid 128 x 256, batched loads.
__global__ __launch_bounds__(256) void k3b_reduce(
    const float* __restrict__ kpart, const float* __restrict__ bo,
    float* __restrict__ out, int KT)
{
    const int g = blockIdx.x * 256 + threadIdx.x;
    const float4* kp = (const float4*)kpart;
    float4 a = make_float4(0.f, 0.f, 0.f, 0.f);
    float4 b = make_float4(0.f, 0.f, 0.f, 0.f);
    float4 cacc = make_float4(0.f, 0.f, 0.f, 0.f);
    float4 d = make_float4(0.f, 0.f, 0.f, 0.f);
    int t = 0;
    for (; t + 3 < KT; t += 4) {
        const float4 v0 = kp[(size_t)(t + 0) * (kB * kH / 4) + g];
        const float4 v1 = kp[(size_t)(t + 1) * (kB * kH / 4) + g];
        const float4 v2 = kp[(size_t)(t + 2) * (kB * kH / 4) + g];
        const float4 v3 = kp[(size_t)(t + 3) * (kB * kH / 4) + g];
        a.x += v0.x; a.y += v0.y; a.z += v0.z; a.w += v0.w;
        b.x += v1.x; b.y += v1.y; b.z += v1.z; b.w += v1.w;
        cacc.x += v2.x; cacc.y += v2.y; cacc.z += v2.z; cacc.w += v2.w;
        d.x += v3.x; d.y += v3.y; d.z += v3.z; d.w += v3.w;
    }
    for (; t < KT; ++t) {
        const float4 v0 = kp[(size_t)t * (kB * kH / 4) + g];
        a.x += v0.x; a.y += v0.y; a.z += v0.z; a.w += v0.w;
    }
    a.x += b.x + cacc.x + d.x;
    a.y += b.y + cacc.y + d.y;
    a.z += b.z + cacc.z + d.z;
    a.w += b.w + cacc.w + d.w;
    const float4 bq = ((const float4*)bo)[g & 255];
    a.x += bq.x; a.y += bq.y; a.z += bq.z; a.w += bq.w;
    ((float4*)out)[g] = a;
}

// ---------------------------------------------------------------------------
extern "C" void kernel_launch(void* const* d_in, const int* in_sizes, int n_in,
                              void* d_out, int out_size, void* d_ws, size_t ws_size,
                              hipStream_t stream) {
    const float* pd   = (const float*)d_in[0];
    const int*   plen = (const int*)  d_in[1];
    const int*   bnum = (const int*)  d_in[2];
    const float* pimg = (const float*)d_in[3];
    const float* W1   = (const float*)d_in[4];
    const float* b1   = (const float*)d_in[5];
    const float* lng  = (const float*)d_in[6];
    const float* lnb  = (const float*)d_in[7];
    const float* W2   = (const float*)d_in[8];
    const float* b2   = (const float*)d_in[9];
    const float* btab = (const float*)d_in[10];
    const float* cw   = (const float*)d_in[11];
    const float* cb   = (const float*)d_in[12];
    const float* Wo   = (const float*)d_in[13];
    const float* bo   = (const float*)d_in[14];
    float* out = (float*)d_out;

    int C = 2048;
    {
        const int Cs[3] = {8192, 4096, 2048};
        for (int i = 0; i < 3; ++i) {
            const size_t need = ((size_t)Cs[i] * 256 + (size_t)kB * kH + 768 + 256 + 132) * 4 +
                                (size_t)Cs[i] * 16 + (size_t)kB * kP * 4 + 256;
            if (ws_size >= need) { C = Cs[i]; break; }
        }
    }
    const int K  = (kB * kP + C - 129) / (C - 128);  // >=1 chain per batch
    const int KT = C / 512;                          // kpart fits in partial

    float* partial  = (float*)d_ws;                  // C*256 floats
    float* combined = partial + (size_t)C * 256;     // 128*1024 floats
    float* Wp       = combined + (size_t)kB * kH;    // 768 floats
    float* bpp      = Wp + 768;                      // 256 floats
    int*   cs_g     = (int*)(bpp + 256);             // 132 ints
    int4*  ctab     = (int4*)(cs_g + 132);           // C int4 (16B-aligned)
    float* rstdb    = (float*)(ctab + C);            // 128*2048 floats (1 MB)
    float* kpart    = partial;                       // alias: dead after k2

    k0_setup<<<dim3(C / 256 + kRSTD_BLOCKS), 256, 0, stream>>>(
        plen, W1, b1, lng, pd, Wp, bpp, cs_g, ctab, rstdb, C, K);
    k1_pd_partial<<<dim3(C / 4), 256, 0, stream>>>(pd, Wp, bpp, lnb, ctab, rstdb, partial);
    k2_combined<<<dim3(kB, 2), 256, 0, stream>>>(partial, plen, W2, b2, bnum, btab,
                                                 pimg, cw, cb, combined, cs_g);
    k3a_outproj<<<dim3(32, KT), 256, 0, stream>>>(combined, Wo, kpart, KT);
    k3b_reduce<<<dim3(kB), 256, 0, stream>>>(kpart, bo, out, KT);
}